// Round 11
// baseline (382.745 us; speedup 1.0000x reference)
//
#include <hip/hip_runtime.h>
#include <stdint.h>

typedef unsigned long long u64;
typedef float vf4 __attribute__((ext_vector_type(4)));

#define NB 32
#define N 512
#define MAXD 10
#define NW 8  // u64 words per 512-bit row

// ---------------- K1: binarize + symmetrize + mask -> packed bitset ----------------
__global__ __launch_bounds__(256) void k1_pack(const float* __restrict__ adj,
                                               const int* __restrict__ mask,
                                               u64* __restrict__ gsym) {
    __shared__ float ldsA[64 * 65];
    __shared__ float ldsB[64 * 65];
    __shared__ unsigned char mI[64], mJ[64];
    int p = blockIdx.x;
    int b = blockIdx.y;
    int ti = 0;
    while (p >= 8 - ti) { p -= 8 - ti; ++ti; }
    int tj = ti + p;
    int i0 = ti * 64, j0 = tj * 64;
    int t = threadIdx.x;
    if (t < 64) mI[t] = (mask[b * N + i0 + t] != 0);
    else if (t < 128) mJ[t - 64] = (mask[b * N + j0 + (t - 64)] != 0);
    const float* Ab = adj + (size_t)b * N * N;
    #pragma unroll
    for (int s = 0; s < 4; ++s) {
        int idx = t + 256 * s;
        int r = idx >> 4, c4 = idx & 15;
        float4 va = *(const float4*)&Ab[(size_t)(i0 + r) * N + j0 + c4 * 4];
        float4 vb = *(const float4*)&Ab[(size_t)(j0 + r) * N + i0 + c4 * 4];
        int o = r * 65 + c4 * 4;
        ldsA[o] = va.x; ldsA[o + 1] = va.y; ldsA[o + 2] = va.z; ldsA[o + 3] = va.w;
        ldsB[o] = vb.x; ldsB[o + 1] = vb.y; ldsB[o + 2] = vb.z; ldsB[o + 3] = vb.w;
    }
    __syncthreads();
    int wave = t >> 6, lane = t & 63;
    for (int s = 0; s < 16; ++s) {
        int r = wave * 16 + s;
        bool bit = ((ldsA[r * 65 + lane] > 0.5f) || (ldsB[lane * 65 + r] > 0.5f))
                   && mI[r] && mJ[lane];
        u64 word = __ballot(bit);
        if (lane == 0) gsym[((size_t)b * N + i0 + r) * NW + tj] = word;
    }
    for (int s = 0; s < 16; ++s) {
        int r = wave * 16 + s;
        bool bit = ((ldsB[r * 65 + lane] > 0.5f) || (ldsA[lane * 65 + r] > 0.5f))
                   && mJ[r] && mI[lane];
        u64 word = __ballot(bit);
        if (lane == 0) gsym[((size_t)b * N + j0 + r) * NW + ti] = word;
    }
}

// spread 8 bits -> u64 of 8 bytes each 0/1
__device__ __forceinline__ u64 spread8(unsigned b) {
    u64 x = (u64)(b * 0x01010101u);
    x |= x << 32;
    x &= 0x8040201008040201ULL;
    x += 0x7f7f7f7f7f7f7f7fULL;
    return (x >> 7) & 0x0101010101010101ULL;
}

// ---------------- K2: bitset BFS, branch-free distance accumulation ----------------
__global__ __launch_bounds__(64) void k2_bfs(const u64* __restrict__ gsym,
                                             const int* __restrict__ mask,
                                             u64* __restrict__ distg64) {
    __shared__ u64 adjT[NW * N];
    __shared__ u64 outB[64 * 65];
    int blk = blockIdx.x;
    int b = blk >> 3;
    int r0 = (blk & 7) * 64;
    int t = threadIdx.x;
    const u64* gs = gsym + (size_t)b * N * NW;
    for (int q = t; q < N * NW; q += 64) {
        u64 w = gs[q];
        adjT[(q & 7) * N + (q >> 3)] = w;
    }
    __syncthreads();

    int i = r0 + t;
    bool mi = mask[b * N + i] != 0;
    u64 c0[NW], c1[NW], c2[NW], c3[NW];
    #pragma unroll
    for (int w = 0; w < NW; ++w) { c0[w] = 0; c1[w] = 0; c2[w] = 0; c3[w] = 0; }

    if (mi) {
        u64 reach[NW] = {};
        u64 frontier[NW] = {};
        reach[i >> 6] = 1ULL << (i & 63);
        #pragma unroll
        for (int w = 0; w < NW; ++w) frontier[w] = reach[w];
        bool active = true;
        for (int k = 0; k <= MAXD; ++k) {
            #pragma unroll
            for (int w = 0; w < NW; ++w) {
                u64 u = ~reach[w];
                u64 t0 = c0[w] & u; c0[w] ^= u;
                u64 t1 = c1[w] & t0; c1[w] ^= t0;
                u64 t2 = c2[w] & t1; c2[w] ^= t1;
                c3[w] ^= t2;
            }
            if (k == MAXD) break;
            if (active) {
                u64 acc[NW] = {};
                bool sat = false;
                for (int w = 0; w < NW && !sat; ++w) {
                    u64 f = frontier[w];
                    while (f) {
                        int j = (w << 6) + __builtin_ctzll(f);
                        f &= f - 1;
                        #pragma unroll
                        for (int e = 0; e < NW; ++e) acc[e] |= adjT[e * N + j];
                        u64 all = acc[0];
                        #pragma unroll
                        for (int e = 1; e < NW; ++e) all &= acc[e];
                        if (all == ~0ULL) { sat = true; break; }
                    }
                }
                bool any = false;
                #pragma unroll
                for (int w = 0; w < NW; ++w) {
                    u64 nf = acc[w] & ~reach[w];
                    frontier[w] = nf;
                    reach[w] |= nf;
                    any = any || (nf != 0);
                }
                active = any;
            }
        }
    } else {
        #pragma unroll
        for (int w = 0; w < NW; ++w) { c0[w] = ~0ULL; c1[w] = ~0ULL; c3[w] = ~0ULL; }
    }

    #pragma unroll
    for (int w = 0; w < NW; ++w) {
        #pragma unroll
        for (int h = 0; h < 8; ++h) {
            unsigned b0 = (unsigned)(c0[w] >> (8 * h)) & 0xFF;
            unsigned b1 = (unsigned)(c1[w] >> (8 * h)) & 0xFF;
            unsigned b2 = (unsigned)(c2[w] >> (8 * h)) & 0xFF;
            unsigned b3 = (unsigned)(c3[w] >> (8 * h)) & 0xFF;
            outB[t * 65 + w * 8 + h] =
                spread8(b0) | (spread8(b1) << 1) | (spread8(b2) << 2) | (spread8(b3) << 3);
        }
    }
    __syncthreads();
    u64* dg = distg64 + (size_t)blk * 64 * 64;
    for (int q = t; q < 64 * 64; q += 64)
        dg[q] = outB[(q >> 6) * 65 + (q & 63)];
}

// ---------------- K3: decoupled gather-store expansion ----------------
// 2048 blocks x 256 thr. Embedding table lives in REGISTERS (lane m<24 holds
// table vf4 m); lookup = 4 ds_bpermute (no L2, no LDS storage, ~30cyc, batchable).
// All 32 dist bytes per thread prefetched into a register array BEFORE the
// store loop: loads never gate stores -> store stream is structurally
// identical to the harness fill (which runs 6.2 TB/s).
#define K3_THREADS (2048 * 256)
#define K3_ITERS   32          // K3_SLOTS / K3_THREADS; 16,777,216 vf4 total
__global__ __launch_bounds__(256) void k3_expand(const unsigned char* __restrict__ dist,
                                                 const float* __restrict__ emb,
                                                 vf4* __restrict__ out4) {
    int t = threadIdx.x;
    int lane = t & 63;
    vf4 tab = {0.f, 0.f, 0.f, 0.f};
    if (lane < 24) tab = ((const vf4*)emb)[lane];   // table vf4 m = half (m&1) of emb row m>>1
    int hoff = (t & 1) << 2;                        // (q&1)*4 : q parity == t parity
    size_t gid = (size_t)blockIdx.x * 256 + t;

    unsigned dv[K3_ITERS];
    #pragma unroll
    for (int it = 0; it < K3_ITERS; ++it)           // 32 independent ubyte loads, all in flight
        dv[it] = dist[(gid + (size_t)it * K3_THREADS) >> 1];
    #pragma unroll
    for (int it = 0; it < K3_ITERS; ++it) {
        int a = ((int)dv[it] << 3) + hoff;          // byte addr = source_lane*4, lane = d*2+(q&1)
        vf4 v;
        v.x = __int_as_float(__builtin_amdgcn_ds_bpermute(a, __float_as_int(tab.x)));
        v.y = __int_as_float(__builtin_amdgcn_ds_bpermute(a, __float_as_int(tab.y)));
        v.z = __int_as_float(__builtin_amdgcn_ds_bpermute(a, __float_as_int(tab.z)));
        v.w = __int_as_float(__builtin_amdgcn_ds_bpermute(a, __float_as_int(tab.w)));
        out4[gid + (size_t)it * K3_THREADS] = v;    // coalesced 1KB/wave, fire-and-forget
    }
}

extern "C" void kernel_launch(void* const* d_in, const int* in_sizes, int n_in,
                              void* d_out, int out_size, void* d_ws, size_t ws_size,
                              hipStream_t stream) {
    const float* adj = (const float*)d_in[0];
    const int* mask = (const int*)d_in[1];  // jnp bool -> int32 per harness convention
    const float* emb = (const float*)d_in[2];
    u64* gsym = (u64*)d_ws;                                                 // 1 MB
    unsigned char* distg = (unsigned char*)d_ws + (size_t)NB * N * NW * 8;  // 8 MB
    k1_pack<<<dim3(36, NB), 256, 0, stream>>>(adj, mask, gsym);
    k2_bfs<<<dim3(NB * 8), 64, 0, stream>>>(gsym, mask, (u64*)distg);
    k3_expand<<<dim3(2048), 256, 0, stream>>>(distg, emb, (vf4*)d_out);
}

// Round 12
// 368.326 us; speedup vs baseline: 1.0391x; 1.0391x over previous
//
#include <hip/hip_runtime.h>
#include <stdint.h>

typedef unsigned long long u64;
typedef float vf4 __attribute__((ext_vector_type(4)));

#define NB 32
#define N 512
#define MAXD 10
#define NW 8  // u64 words per 512-bit row

// ---------------- K1: binarize + symmetrize + mask -> packed bitset ----------------
__global__ __launch_bounds__(256) void k1_pack(const float* __restrict__ adj,
                                               const int* __restrict__ mask,
                                               u64* __restrict__ gsym) {
    __shared__ float ldsA[64 * 65];
    __shared__ float ldsB[64 * 65];
    __shared__ unsigned char mI[64], mJ[64];
    int p = blockIdx.x;
    int b = blockIdx.y;
    int ti = 0;
    while (p >= 8 - ti) { p -= 8 - ti; ++ti; }
    int tj = ti + p;
    int i0 = ti * 64, j0 = tj * 64;
    int t = threadIdx.x;
    if (t < 64) mI[t] = (mask[b * N + i0 + t] != 0);
    else if (t < 128) mJ[t - 64] = (mask[b * N + j0 + (t - 64)] != 0);
    const float* Ab = adj + (size_t)b * N * N;
    #pragma unroll
    for (int s = 0; s < 4; ++s) {
        int idx = t + 256 * s;
        int r = idx >> 4, c4 = idx & 15;
        float4 va = *(const float4*)&Ab[(size_t)(i0 + r) * N + j0 + c4 * 4];
        float4 vb = *(const float4*)&Ab[(size_t)(j0 + r) * N + i0 + c4 * 4];
        int o = r * 65 + c4 * 4;
        ldsA[o] = va.x; ldsA[o + 1] = va.y; ldsA[o + 2] = va.z; ldsA[o + 3] = va.w;
        ldsB[o] = vb.x; ldsB[o + 1] = vb.y; ldsB[o + 2] = vb.z; ldsB[o + 3] = vb.w;
    }
    __syncthreads();
    int wave = t >> 6, lane = t & 63;
    for (int s = 0; s < 16; ++s) {
        int r = wave * 16 + s;
        bool bit = ((ldsA[r * 65 + lane] > 0.5f) || (ldsB[lane * 65 + r] > 0.5f))
                   && mI[r] && mJ[lane];
        u64 word = __ballot(bit);
        if (lane == 0) gsym[((size_t)b * N + i0 + r) * NW + tj] = word;
    }
    for (int s = 0; s < 16; ++s) {
        int r = wave * 16 + s;
        bool bit = ((ldsB[r * 65 + lane] > 0.5f) || (ldsA[lane * 65 + r] > 0.5f))
                   && mJ[r] && mI[lane];
        u64 word = __ballot(bit);
        if (lane == 0) gsym[((size_t)b * N + j0 + r) * NW + ti] = word;
    }
}

// spread 8 bits -> u64 of 8 bytes each 0/1
__device__ __forceinline__ u64 spread8(unsigned b) {
    u64 x = (u64)(b * 0x01010101u);
    x |= x << 32;
    x &= 0x8040201008040201ULL;
    x += 0x7f7f7f7f7f7f7f7fULL;
    return (x >> 7) & 0x0101010101010101ULL;
}

// ---------------- K2: bitset BFS, branch-free distance accumulation ----------------
__global__ __launch_bounds__(64) void k2_bfs(const u64* __restrict__ gsym,
                                             const int* __restrict__ mask,
                                             u64* __restrict__ distg64) {
    __shared__ u64 adjT[NW * N];
    __shared__ u64 outB[64 * 65];
    int blk = blockIdx.x;
    int b = blk >> 3;
    int r0 = (blk & 7) * 64;
    int t = threadIdx.x;
    const u64* gs = gsym + (size_t)b * N * NW;
    for (int q = t; q < N * NW; q += 64) {
        u64 w = gs[q];
        adjT[(q & 7) * N + (q >> 3)] = w;
    }
    __syncthreads();

    int i = r0 + t;
    bool mi = mask[b * N + i] != 0;
    u64 c0[NW], c1[NW], c2[NW], c3[NW];
    #pragma unroll
    for (int w = 0; w < NW; ++w) { c0[w] = 0; c1[w] = 0; c2[w] = 0; c3[w] = 0; }

    if (mi) {
        u64 reach[NW] = {};
        u64 frontier[NW] = {};
        reach[i >> 6] = 1ULL << (i & 63);
        #pragma unroll
        for (int w = 0; w < NW; ++w) frontier[w] = reach[w];
        bool active = true;
        for (int k = 0; k <= MAXD; ++k) {
            #pragma unroll
            for (int w = 0; w < NW; ++w) {
                u64 u = ~reach[w];
                u64 t0 = c0[w] & u; c0[w] ^= u;
                u64 t1 = c1[w] & t0; c1[w] ^= t0;
                u64 t2 = c2[w] & t1; c2[w] ^= t1;
                c3[w] ^= t2;
            }
            if (k == MAXD) break;
            if (active) {
                u64 acc[NW] = {};
                bool sat = false;
                for (int w = 0; w < NW && !sat; ++w) {
                    u64 f = frontier[w];
                    while (f) {
                        int j = (w << 6) + __builtin_ctzll(f);
                        f &= f - 1;
                        #pragma unroll
                        for (int e = 0; e < NW; ++e) acc[e] |= adjT[e * N + j];
                        u64 all = acc[0];
                        #pragma unroll
                        for (int e = 1; e < NW; ++e) all &= acc[e];
                        if (all == ~0ULL) { sat = true; break; }
                    }
                }
                bool any = false;
                #pragma unroll
                for (int w = 0; w < NW; ++w) {
                    u64 nf = acc[w] & ~reach[w];
                    frontier[w] = nf;
                    reach[w] |= nf;
                    any = any || (nf != 0);
                }
                active = any;
            }
        }
    } else {
        #pragma unroll
        for (int w = 0; w < NW; ++w) { c0[w] = ~0ULL; c1[w] = ~0ULL; c3[w] = ~0ULL; }
    }

    #pragma unroll
    for (int w = 0; w < NW; ++w) {
        #pragma unroll
        for (int h = 0; h < 8; ++h) {
            unsigned b0 = (unsigned)(c0[w] >> (8 * h)) & 0xFF;
            unsigned b1 = (unsigned)(c1[w] >> (8 * h)) & 0xFF;
            unsigned b2 = (unsigned)(c2[w] >> (8 * h)) & 0xFF;
            unsigned b3 = (unsigned)(c3[w] >> (8 * h)) & 0xFF;
            outB[t * 65 + w * 8 + h] =
                spread8(b0) | (spread8(b1) << 1) | (spread8(b2) << 2) | (spread8(b3) << 3);
        }
    }
    __syncthreads();
    u64* dg = distg64 + (size_t)blk * 64 * 64;
    for (int q = t; q < 64 * 64; q += 64)
        dg[q] = outB[(q >> 6) * 65 + (q & 63)];
}

// ---------------- K3: fill-mimic expansion — ONE 16B store per thread ----------------
// 65536 blocks x 256 threads = 16,777,216 threads = #vf4 slots. Per thread:
// one ubyte dist load (32 consecutive bytes per wave = single 32B fetch),
// 4 ds_bpermute register-table lookups, one coalesced dwordx4 store, exit.
// Structurally identical to __amd_rocclr_fillBufferAligned (which sustains
// 6.0 TB/s at ~3 waves/CU): no store loop, no LDS, no syncthreads, tiny VGPR.
__global__ __launch_bounds__(256) void k3_expand(const unsigned char* __restrict__ dist,
                                                 const float* __restrict__ emb,
                                                 vf4* __restrict__ out4) {
    int t = threadIdx.x;
    int lane = t & 63;
    vf4 tab = {0.f, 0.f, 0.f, 0.f};
    if (lane < 24) tab = ((const vf4*)emb)[lane];   // lane m holds half (m&1) of emb row m>>1
    size_t q = (size_t)blockIdx.x * 256 + t;        // vf4 slot
    unsigned d = dist[q >> 1];
    int a = ((int)d << 3) + ((t & 1) << 2);         // src lane = d*2+(q&1), byte addr = lane*4
    vf4 v;
    v.x = __int_as_float(__builtin_amdgcn_ds_bpermute(a, __float_as_int(tab.x)));
    v.y = __int_as_float(__builtin_amdgcn_ds_bpermute(a, __float_as_int(tab.y)));
    v.z = __int_as_float(__builtin_amdgcn_ds_bpermute(a, __float_as_int(tab.z)));
    v.w = __int_as_float(__builtin_amdgcn_ds_bpermute(a, __float_as_int(tab.w)));
    out4[q] = v;
}

extern "C" void kernel_launch(void* const* d_in, const int* in_sizes, int n_in,
                              void* d_out, int out_size, void* d_ws, size_t ws_size,
                              hipStream_t stream) {
    const float* adj = (const float*)d_in[0];
    const int* mask = (const int*)d_in[1];  // jnp bool -> int32 per harness convention
    const float* emb = (const float*)d_in[2];
    u64* gsym = (u64*)d_ws;                                                 // 1 MB
    unsigned char* distg = (unsigned char*)d_ws + (size_t)NB * N * NW * 8;  // 8 MB
    k1_pack<<<dim3(36, NB), 256, 0, stream>>>(adj, mask, gsym);
    k2_bfs<<<dim3(NB * 8), 64, 0, stream>>>(gsym, mask, (u64*)distg);
    k3_expand<<<dim3(65536), 256, 0, stream>>>(distg, emb, (vf4*)d_out);
}